// Round 4
// baseline (247.453 us; speedup 1.0000x reference)
//
#include <hip/hip_runtime.h>
#include <math.h>

#define BB 8
#define LL 4096
#define HH 512
#define NN 512
#define TT 192        // truncated FIR length
#define NS 96         // tap-pair steps (TT/2)
#define LT 16         // output rows per wave tile

typedef _Float16 half2_t __attribute__((ext_vector_type(2)));
typedef unsigned int u32;
typedef unsigned short u16;

#if __has_builtin(__builtin_amdgcn_fdot2)
__device__ __forceinline__ float fdot2(half2_t a, half2_t b, float c) {
    return __builtin_amdgcn_fdot2(a, b, c, false);
}
#else
__device__ __forceinline__ float fdot2(half2_t a, half2_t b, float c) {
    return c + (float)a.x * (float)b.x + (float)a.y * (float)b.y;
}
#endif

// ---------------------------------------------------------------------------
// Kernel 1 (fused prep), 3 branches by blockIdx:
//   [0, 4096)     : LayerNorm + fp16 pack of adjacent L-row pairs
//   [4096, 4160)  : transpose+pack C [H,N] -> Cpk[N,H] float2(cr,ci)
//   [4160, 4672)  : PQ[n][t] = float2(Re(s_n w_n^t), Im(s_n w_n^t))
#define LN_BLKS (BB * LL / 8)
__global__ __launch_bounds__(256) void prep_kernel(const float* __restrict__ x,
                                                   const float* __restrict__ w,
                                                   const float* __restrict__ bia,
                                                   const float* __restrict__ Cr,
                                                   const float* __restrict__ Ci,
                                                   const float* __restrict__ LR,
                                                   const float* __restrict__ LI,
                                                   u32* __restrict__ u2,
                                                   float2* __restrict__ Cpk,
                                                   float2* __restrict__ PQ) {
    __shared__ float tile[64][65];
    if (blockIdx.x >= LN_BLKS + 64) {
        // ---- PQ branch: one n per block, t = tid (192 of 256 active) ----
        int n = blockIdx.x - (LN_BLKS + 64);
        int t = threadIdx.x;
        if (t < TT) {
            float lr = -expf(LR[n]);
            float li = expf(LI[n]);
            float el = expf(lr);
            float sn, cs;
            sincosf(li, &sn, &cs);
            float nr = el * cs - 1.0f;
            float ni = el * sn;
            float inv = 1.0f / (lr * lr + li * li);
            float sr = (nr * lr + ni * li) * inv;   // s = (e^lam-1)/lam
            float si = (ni * lr - nr * li) * inv;
            float tf = (float)t;
            float e2 = expf(lr * tf);
            float s2, c2;
            sincosf(li * tf, &s2, &c2);
            float er = e2 * c2, ei = e2 * s2;       // w^t
            PQ[(size_t)n * TT + t] = make_float2(sr * er - si * ei, sr * ei + si * er);
        }
        return;
    }
    if (blockIdx.x >= LN_BLKS) {
        // ---- transpose+pack branch: single tile, R then I ----
        int tb = blockIdx.x - LN_BLKS;   // 0..63
        int h0 = (tb & 7) * 64;
        int n0 = (tb >> 3) * 64;
        int c = threadIdx.x & 63;
        int r0 = threadIdx.x >> 6;
        float vr[16], vi[16];
        #pragma unroll
        for (int i = 0; i < 16; ++i) {
            int r = r0 + i * 4;
            tile[r][c] = Cr[(size_t)(h0 + r) * NN + n0 + c];
        }
        __syncthreads();
        #pragma unroll
        for (int i = 0; i < 16; ++i) vr[i] = tile[c][r0 + i * 4];
        __syncthreads();
        #pragma unroll
        for (int i = 0; i < 16; ++i) {
            int r = r0 + i * 4;
            tile[r][c] = Ci[(size_t)(h0 + r) * NN + n0 + c];
        }
        __syncthreads();
        #pragma unroll
        for (int i = 0; i < 16; ++i) vi[i] = tile[c][r0 + i * 4];
        #pragma unroll
        for (int i = 0; i < 16; ++i) {
            int r = r0 + i * 4;
            Cpk[(size_t)(n0 + r) * HH + h0 + c] = make_float2(vr[i], vi[i]);
        }
        return;
    }
    // ---- layernorm branch: one wave per L-row pair ----
    int wave = threadIdx.x >> 6;
    int lane = threadIdx.x & 63;
    size_t pair = (size_t)blockIdx.x * 4 + wave;
    const float* xr0 = x + pair * 2 * HH;
    const float* xr1 = xr0 + HH;
    float4 a0 = *(const float4*)(xr0 + lane * 4);
    float4 a1 = *(const float4*)(xr0 + 256 + lane * 4);
    float4 b0 = *(const float4*)(xr1 + lane * 4);
    float4 b1 = *(const float4*)(xr1 + 256 + lane * 4);
    float sA  = a0.x + a0.y + a0.z + a0.w + a1.x + a1.y + a1.z + a1.w;
    float qA  = a0.x*a0.x + a0.y*a0.y + a0.z*a0.z + a0.w*a0.w
              + a1.x*a1.x + a1.y*a1.y + a1.z*a1.z + a1.w*a1.w;
    float sB  = b0.x + b0.y + b0.z + b0.w + b1.x + b1.y + b1.z + b1.w;
    float qB  = b0.x*b0.x + b0.y*b0.y + b0.z*b0.z + b0.w*b0.w
              + b1.x*b1.x + b1.y*b1.y + b1.z*b1.z + b1.w*b1.w;
    #pragma unroll
    for (int off = 1; off < 64; off <<= 1) {
        sA += __shfl_xor(sA, off, 64);
        qA += __shfl_xor(qA, off, 64);
        sB += __shfl_xor(sB, off, 64);
        qB += __shfl_xor(qB, off, 64);
    }
    float mA = sA * (1.0f / 512.0f);
    float rA = rsqrtf(qA * (1.0f / 512.0f) - mA * mA + 1e-5f);
    float mB = sB * (1.0f / 512.0f);
    float rB = rsqrtf(qB * (1.0f / 512.0f) - mB * mB + 1e-5f);
    float4 w0 = *(const float4*)(w + lane * 4);
    float4 w1 = *(const float4*)(w + 256 + lane * 4);
    float4 c0 = *(const float4*)(bia + lane * 4);
    float4 c1 = *(const float4*)(bia + 256 + lane * 4);
    uint4 o0, o1;
    {
        half2_t p;
        p.x = (_Float16)((a0.x - mA) * rA * w0.x + c0.x);
        p.y = (_Float16)((b0.x - mB) * rB * w0.x + c0.x);
        o0.x = __builtin_bit_cast(u32, p);
        p.x = (_Float16)((a0.y - mA) * rA * w0.y + c0.y);
        p.y = (_Float16)((b0.y - mB) * rB * w0.y + c0.y);
        o0.y = __builtin_bit_cast(u32, p);
        p.x = (_Float16)((a0.z - mA) * rA * w0.z + c0.z);
        p.y = (_Float16)((b0.z - mB) * rB * w0.z + c0.z);
        o0.z = __builtin_bit_cast(u32, p);
        p.x = (_Float16)((a0.w - mA) * rA * w0.w + c0.w);
        p.y = (_Float16)((b0.w - mB) * rB * w0.w + c0.w);
        o0.w = __builtin_bit_cast(u32, p);
        p.x = (_Float16)((a1.x - mA) * rA * w1.x + c1.x);
        p.y = (_Float16)((b1.x - mB) * rB * w1.x + c1.x);
        o1.x = __builtin_bit_cast(u32, p);
        p.x = (_Float16)((a1.y - mA) * rA * w1.y + c1.y);
        p.y = (_Float16)((b1.y - mB) * rB * w1.y + c1.y);
        o1.y = __builtin_bit_cast(u32, p);
        p.x = (_Float16)((a1.z - mA) * rA * w1.z + c1.z);
        p.y = (_Float16)((b1.z - mB) * rB * w1.z + c1.z);
        o1.z = __builtin_bit_cast(u32, p);
        p.x = (_Float16)((a1.w - mA) * rA * w1.w + c1.w);
        p.y = (_Float16)((b1.w - mB) * rB * w1.w + c1.w);
        o1.w = __builtin_bit_cast(u32, p);
    }
    *(uint4*)(u2 + pair * HH + lane * 4) = o0;
    *(uint4*)(u2 + pair * HH + 256 + lane * 4) = o1;
}

// ---------------------------------------------------------------------------
// Kernel 2: KT[t][h] = sum_n cr*P[n][t] - ci*Q[n][t].  2 t's per block,
// h-half per block (192 blocks); PQ loads wave-uniform, Cpk coalesced float2.
__global__ __launch_bounds__(256) void build_kt(const float2* __restrict__ Cpk,
                                                const float2* __restrict__ PQ,
                                                float* __restrict__ KT) {
    int blk = blockIdx.x;
    int t0 = (blk >> 1) * 2;
    int half = blk & 1;
    int h = half * 256 + threadIdx.x;
    float k0 = 0.0f, k1 = 0.0f;
    const float4* pq4 = (const float4*)PQ;
    int pqoff = t0 >> 1;
    #pragma unroll 8
    for (int n = 0; n < NN; ++n) {
        float2 c = Cpk[(size_t)n * HH + h];
        float4 f = pq4[(size_t)n * (TT / 2) + pqoff];   // (P[t0],Q[t0],P[t0+1],Q[t0+1])
        k0 = fmaf(c.x, f.x, k0);
        k0 = fmaf(-c.y, f.y, k0);
        k1 = fmaf(c.x, f.z, k1);
        k1 = fmaf(-c.y, f.w, k1);
    }
    KT[(size_t)t0 * HH + h] = k0;
    KT[(size_t)(t0 + 1) * HH + h] = k1;
}

// ---------------------------------------------------------------------------
// Kernel 3: pack K into step-indexed swapped half2 pairs (coalesced writes).
// KQ[s][h].x = kx = (lo K[191-2s], hi K[190-2s])   (odd-j pair)
// KQ[s][h].y = ky = (lo K[192-2s] (0 @s=0), hi K[191-2s])  (even-j pair)
__global__ void pack_k(const float* __restrict__ KT, uint2* __restrict__ KQ) {
    int idx = blockIdx.x * 256 + threadIdx.x;   // NS*HH entries
    int s = idx >> 9;
    int h = idx & 511;
    float k0 = KT[(190 - 2 * s) * HH + h];
    float k1 = KT[(191 - 2 * s) * HH + h];
    float k2 = (s == 0) ? 0.0f : KT[(192 - 2 * s) * HH + h];
    half2_t kx, ky;
    kx.x = (_Float16)k1; kx.y = (_Float16)k0;
    ky.x = (_Float16)k2; ky.y = (_Float16)k1;
    KQ[idx] = make_uint2(__builtin_bit_cast(u32, kx), __builtin_bit_cast(u32, ky));
}

// ---------------------------------------------------------------------------
// Kernel 4: causal FIR conv via v_dot2_f32_f16 + D*u residual.
// Block = 64 h x 8 l-tile waves (512 threads).  All taps for the block's 64-h
// slice staged in LDS once (48 KB): tap reads are ds_read_b64 with
// compile-time offsets, no K registers, no K ring.
// __launch_bounds__(512, 4): min 4 waves/SIMD -> 128-VGPR budget.  R3 counters
// showed VGPR_Count=48 with ~48 live values (acc[16]+A[16]+B[16]) => the
// default budget forced AGPR/scratch spills (~2.4k extra VALU ops/wave,
// 61% of VALU work).  128 VGPR holds the rings spill-free; LDS still admits
// 2 blocks/CU (16 waves).
// u: 2x16 register ring, prefetched 32 steps ahead.  u2 padded 16 rows.

template <bool PRED>
__device__ __forceinline__ u32 load_v(const u32* __restrict__ ub2, int vi) {
    int c = vi;
    if (PRED && c < 0) c = 0;
    u32 val = ub2[(size_t)c * HH];
    if (PRED && vi < 0) val = 0u;
    return val;
}

#define SLOT(p) ((p) < 16 ? W[(p)] : X[(p) - 16])

// One 16-step block; W holds v[R..R+15], X v[R+16..R+31], R = Vm1+16*sb.
// Step k: taps from LDS at (soff+k), consumes SLOT(k+m)/(k+m+1);
// if LOADU, loads v[ubase+k] into dead slot W[k].
template <bool PRED, bool LOADU>
__device__ __forceinline__ void conv_block(const u32* __restrict__ ub2,
                                           const uint2* klds,
                                           float (&acc)[LT], u32 (&W)[16], u32 (&X)[16],
                                           int ubase, int soff) {
    #pragma unroll
    for (int k = 0; k < 16; ++k) {
        u32 nv = 0u;
        if (LOADU) nv = load_v<PRED>(ub2, ubase + k);
        uint2 kq = klds[(soff + k) * 64];
        half2_t kx = __builtin_bit_cast(half2_t, kq.x);
        half2_t ky = __builtin_bit_cast(half2_t, kq.y);
        #pragma unroll
        for (int m = 0; m < 8; ++m) {
            half2_t ve = __builtin_bit_cast(half2_t, SLOT(k + m));
            half2_t vo = __builtin_bit_cast(half2_t, SLOT(k + m + 1));
            acc[2 * m]     = fdot2(ve, ky, acc[2 * m]);
            acc[2 * m + 1] = fdot2(vo, kx, acc[2 * m + 1]);
        }
        if (LOADU) W[k] = nv;
    }
}

template <bool PRED>
__device__ __forceinline__ void conv_all(const u32* __restrict__ ub2,
                                         const uint2* klds,
                                         float (&acc)[LT], u32 (&A)[16], u32 (&B)[16],
                                         int Vm1) {
    #pragma unroll
    for (int j = 0; j < 16; ++j) A[j] = load_v<PRED>(ub2, Vm1 + j);
    #pragma unroll
    for (int j = 0; j < 16; ++j) B[j] = load_v<PRED>(ub2, Vm1 + 16 + j);
    #pragma unroll 1
    for (int sbp = 0; sbp < 2; ++sbp) {   // sb = 0..3
        conv_block<PRED, true>(ub2, klds, acc, A, B, Vm1 + 32 + 32 * sbp, 32 * sbp);
        conv_block<PRED, true>(ub2, klds, acc, B, A, Vm1 + 48 + 32 * sbp, 32 * sbp + 16);
    }
    // sb = 4: loads v[Vm1+96..111] = v[l0/2..l0/2+15] into A (epilogue data)
    conv_block<PRED, true>(ub2, klds, acc, A, B, Vm1 + 96, 64);
    // sb = 5: no loads; A preserved
    conv_block<PRED, false>(ub2, klds, acc, B, A, 0, 80);
}

__global__ __launch_bounds__(512, 4) void conv_kernel(const u32* __restrict__ u2,
                                                      const uint2* __restrict__ KQ,
                                                      const float* __restrict__ KT,
                                                      const float* __restrict__ Dp,
                                                      float* __restrict__ y) {
    __shared__ uint2 KL[NS * 64];        // 48 KB: taps for this block's 64 h's
    int tid = threadIdx.x;
    int lane = tid & 63;
    int g = tid >> 6;                    // wave = l-subtile (0..7)
    int blk = blockIdx.x;
    int hg = blk & 7;                    // 8 h-groups of 64
    int tg = (blk >> 3) & 31;            // 32 tile-groups of 8 tiles
    int b = blk >> 8;                    // 8 batches
    int h = hg * 64 + lane;
    int l0 = (tg * 8 + g) * LT;
    // cooperative K stage: NS*64 uint2 = 3072 uint4 over 512 threads
    {
        const uint2* kg = KQ + hg * 64;
        #pragma unroll
        for (int it = 0; it < (NS * 64 / 2) / 512; ++it) {
            int i = it * 512 + tid;      // uint4 index
            int s = i >> 5;
            int q = i & 31;
            uint4 v = *(const uint4*)(kg + (size_t)s * HH + q * 2);
            *(uint4*)(&KL[s * 64 + q * 2]) = v;
        }
    }
    __syncthreads();
    const u32* ub2 = u2 + (size_t)b * (LL / 2) * HH + h;
    const uint2* klds = &KL[lane];
    int Vm1 = l0 / 2 - NS;
    float acc[LT];
    u32 A[16], B[16];
    #pragma unroll
    for (int j = 0; j < LT; ++j) acc[j] = 0.0f;
    if (l0 >= TT) {
        conv_all<false>(ub2, klds, acc, A, B, Vm1);
    } else {
        conv_all<true>(ub2, klds, acc, A, B, Vm1);
    }
    float dv = Dp[h];
    float k0f = KT[h];          // K[0]
    float ce = k0f + dv;
    float* yb = y + ((size_t)b * LL + l0) * HH + h;
    // A[m] = v[l0/2+m] = (u[l0+2m], u[l0+2m+1])
    #pragma unroll
    for (int m = 0; m < 8; ++m) {
        half2_t av = __builtin_bit_cast(half2_t, A[m]);
        float ue = (float)av.x;
        float uo = (float)av.y;
        yb[(size_t)(2 * m) * HH]     = acc[2 * m] + ce * ue;
        yb[(size_t)(2 * m + 1) * HH] = acc[2 * m + 1] + dv * uo;
    }
}

// ---------------------------------------------------------------------------
extern "C" void kernel_launch(void* const* d_in, const int* in_sizes, int n_in,
                              void* d_out, int out_size, void* d_ws, size_t ws_size,
                              hipStream_t stream) {
    const float* x   = (const float*)d_in[0];
    const float* lnw = (const float*)d_in[1];
    const float* lnb = (const float*)d_in[2];
    const float* LR  = (const float*)d_in[3];
    const float* LI  = (const float*)d_in[4];
    const float* Cr  = (const float*)d_in[5];
    const float* Ci  = (const float*)d_in[6];
    const float* Dp  = (const float*)d_in[7];
    float* y  = (float*)d_out;

    float2* Cpk = (float2*)d_ws;                      // NN*HH float2   (2 MB)
    float2* PQ  = Cpk + (size_t)NN * HH;              // NN*TT float2   (0.75 MB)
    float*  KT  = (float*)(PQ + (size_t)NN * TT);     // TT*HH          (384 KB)
    uint2*  KQ  = (uint2*)(KT + (size_t)TT * HH);     // NS*HH uint2    (384 KB)
    u32*    u2  = (u32*)(KQ + (size_t)NS * HH);       // BB*(LL/2)*HH + 16-row pad

    prep_kernel<<<LN_BLKS + 64 + NN, 256, 0, stream>>>(x, lnw, lnb, Cr, Ci,
                                                       LR, LI, u2, Cpk, PQ);
    build_kt<<<TT, 256, 0, stream>>>(Cpk, PQ, KT);
    pack_k<<<NS * HH / 256, 256, 0, stream>>>(KT, KQ);
    conv_kernel<<<BB * (LL / (8 * LT)) * 8, 512, 0, stream>>>(u2, KQ, KT, Dp, y);
}

// Round 8
// 243.508 us; speedup vs baseline: 1.0162x; 1.0162x over previous
//
#include <hip/hip_runtime.h>
#include <math.h>

#define BB 8
#define LL 4096
#define HH 512
#define NN 512
#define TT 192        // truncated FIR length
#define NS 96         // tap-pair steps (TT/2)
#define LT 16         // output rows per wave tile

typedef _Float16 half2_t __attribute__((ext_vector_type(2)));
typedef unsigned int u32;
typedef unsigned short u16;

// Inline-asm dot2: the "v" constraints pin acc (dst, "+v") and both sources
// to the arch-VGPR register class.  R3/R4 evidence: VGPR_Count=48 (= exactly
// acc[16]+A[16]+B[16], zero temps -> impossible as pure arch allocation),
// no scratch in WRITE_SIZE, occ ~3 waves/SIMD (~170 unified regs/wave):
// the allocator kept the rings in AGPRs and shuttled via v_accvgpr_read/
// write (~1.8k phantom VALU ops/wave).  launch_bounds hints did NOT move it
// (48 VGPR under both default and (512,4)).  Class-pinning makes AGPR
// assignment impossible for these values.
#if defined(__AMDGCN__)
__device__ __forceinline__ float fdot2(half2_t a, half2_t b, float c) {
    asm("v_dot2_f32_f16 %0, %1, %2, %0" : "+v"(c) : "v"(a), "v"(b));
    return c;
}
#elif __has_builtin(__builtin_amdgcn_fdot2)
__device__ __forceinline__ float fdot2(half2_t a, half2_t b, float c) {
    return __builtin_amdgcn_fdot2(a, b, c, false);
}
#else
__device__ __forceinline__ float fdot2(half2_t a, half2_t b, float c) {
    return c + (float)a.x * (float)b.x + (float)a.y * (float)b.y;
}
#endif

// ---------------------------------------------------------------------------
// Kernel 1 (fused prep), 3 branches by blockIdx:
//   [0, 4096)     : LayerNorm + fp16 pack of adjacent L-row pairs
//   [4096, 4160)  : transpose+pack C [H,N] -> Cpk[N,H] float2(cr,ci)
//   [4160, 4672)  : PQ[n][t] = float2(Re(s_n w_n^t), Im(s_n w_n^t))
#define LN_BLKS (BB * LL / 8)
__global__ __launch_bounds__(256) void prep_kernel(const float* __restrict__ x,
                                                   const float* __restrict__ w,
                                                   const float* __restrict__ bia,
                                                   const float* __restrict__ Cr,
                                                   const float* __restrict__ Ci,
                                                   const float* __restrict__ LR,
                                                   const float* __restrict__ LI,
                                                   u32* __restrict__ u2,
                                                   float2* __restrict__ Cpk,
                                                   float2* __restrict__ PQ) {
    __shared__ float tile[64][65];
    if (blockIdx.x >= LN_BLKS + 64) {
        // ---- PQ branch: one n per block, t = tid (192 of 256 active) ----
        int n = blockIdx.x - (LN_BLKS + 64);
        int t = threadIdx.x;
        if (t < TT) {
            float lr = -expf(LR[n]);
            float li = expf(LI[n]);
            float el = expf(lr);
            float sn, cs;
            sincosf(li, &sn, &cs);
            float nr = el * cs - 1.0f;
            float ni = el * sn;
            float inv = 1.0f / (lr * lr + li * li);
            float sr = (nr * lr + ni * li) * inv;   // s = (e^lam-1)/lam
            float si = (ni * lr - nr * li) * inv;
            float tf = (float)t;
            float e2 = expf(lr * tf);
            float s2, c2;
            sincosf(li * tf, &s2, &c2);
            float er = e2 * c2, ei = e2 * s2;       // w^t
            PQ[(size_t)n * TT + t] = make_float2(sr * er - si * ei, sr * ei + si * er);
        }
        return;
    }
    if (blockIdx.x >= LN_BLKS) {
        // ---- transpose+pack branch: single tile, R then I ----
        int tb = blockIdx.x - LN_BLKS;   // 0..63
        int h0 = (tb & 7) * 64;
        int n0 = (tb >> 3) * 64;
        int c = threadIdx.x & 63;
        int r0 = threadIdx.x >> 6;
        float vr[16], vi[16];
        #pragma unroll
        for (int i = 0; i < 16; ++i) {
            int r = r0 + i * 4;
            tile[r][c] = Cr[(size_t)(h0 + r) * NN + n0 + c];
        }
        __syncthreads();
        #pragma unroll
        for (int i = 0; i < 16; ++i) vr[i] = tile[c][r0 + i * 4];
        __syncthreads();
        #pragma unroll
        for (int i = 0; i < 16; ++i) {
            int r = r0 + i * 4;
            tile[r][c] = Ci[(size_t)(h0 + r) * NN + n0 + c];
        }
        __syncthreads();
        #pragma unroll
        for (int i = 0; i < 16; ++i) vi[i] = tile[c][r0 + i * 4];
        #pragma unroll
        for (int i = 0; i < 16; ++i) {
            int r = r0 + i * 4;
            Cpk[(size_t)(n0 + r) * HH + h0 + c] = make_float2(vr[i], vi[i]);
        }
        return;
    }
    // ---- layernorm branch: one wave per L-row pair ----
    int wave = threadIdx.x >> 6;
    int lane = threadIdx.x & 63;
    size_t pair = (size_t)blockIdx.x * 4 + wave;
    const float* xr0 = x + pair * 2 * HH;
    const float* xr1 = xr0 + HH;
    float4 a0 = *(const float4*)(xr0 + lane * 4);
    float4 a1 = *(const float4*)(xr0 + 256 + lane * 4);
    float4 b0 = *(const float4*)(xr1 + lane * 4);
    float4 b1 = *(const float4*)(xr1 + 256 + lane * 4);
    float sA  = a0.x + a0.y + a0.z + a0.w + a1.x + a1.y + a1.z + a1.w;
    float qA  = a0.x*a0.x + a0.y*a0.y + a0.z*a0.z + a0.w*a0.w
              + a1.x*a1.x + a1.y*a1.y + a1.z*a1.z + a1.w*a1.w;
    float sB  = b0.x + b0.y + b0.z + b0.w + b1.x + b1.y + b1.z + b1.w;
    float qB  = b0.x*b0.x + b0.y*b0.y + b0.z*b0.z + b0.w*b0.w
              + b1.x*b1.x + b1.y*b1.y + b1.z*b1.z + b1.w*b1.w;
    #pragma unroll
    for (int off = 1; off < 64; off <<= 1) {
        sA += __shfl_xor(sA, off, 64);
        qA += __shfl_xor(qA, off, 64);
        sB += __shfl_xor(sB, off, 64);
        qB += __shfl_xor(qB, off, 64);
    }
    float mA = sA * (1.0f / 512.0f);
    float rA = rsqrtf(qA * (1.0f / 512.0f) - mA * mA + 1e-5f);
    float mB = sB * (1.0f / 512.0f);
    float rB = rsqrtf(qB * (1.0f / 512.0f) - mB * mB + 1e-5f);
    float4 w0 = *(const float4*)(w + lane * 4);
    float4 w1 = *(const float4*)(w + 256 + lane * 4);
    float4 c0 = *(const float4*)(bia + lane * 4);
    float4 c1 = *(const float4*)(bia + 256 + lane * 4);
    uint4 o0, o1;
    {
        half2_t p;
        p.x = (_Float16)((a0.x - mA) * rA * w0.x + c0.x);
        p.y = (_Float16)((b0.x - mB) * rB * w0.x + c0.x);
        o0.x = __builtin_bit_cast(u32, p);
        p.x = (_Float16)((a0.y - mA) * rA * w0.y + c0.y);
        p.y = (_Float16)((b0.y - mB) * rB * w0.y + c0.y);
        o0.y = __builtin_bit_cast(u32, p);
        p.x = (_Float16)((a0.z - mA) * rA * w0.z + c0.z);
        p.y = (_Float16)((b0.z - mB) * rB * w0.z + c0.z);
        o0.z = __builtin_bit_cast(u32, p);
        p.x = (_Float16)((a0.w - mA) * rA * w0.w + c0.w);
        p.y = (_Float16)((b0.w - mB) * rB * w0.w + c0.w);
        o0.w = __builtin_bit_cast(u32, p);
        p.x = (_Float16)((a1.x - mA) * rA * w1.x + c1.x);
        p.y = (_Float16)((b1.x - mB) * rB * w1.x + c1.x);
        o1.x = __builtin_bit_cast(u32, p);
        p.x = (_Float16)((a1.y - mA) * rA * w1.y + c1.y);
        p.y = (_Float16)((b1.y - mB) * rB * w1.y + c1.y);
        o1.y = __builtin_bit_cast(u32, p);
        p.x = (_Float16)((a1.z - mA) * rA * w1.z + c1.z);
        p.y = (_Float16)((b1.z - mB) * rB * w1.z + c1.z);
        o1.z = __builtin_bit_cast(u32, p);
        p.x = (_Float16)((a1.w - mA) * rA * w1.w + c1.w);
        p.y = (_Float16)((b1.w - mB) * rB * w1.w + c1.w);
        o1.w = __builtin_bit_cast(u32, p);
    }
    *(uint4*)(u2 + pair * HH + lane * 4) = o0;
    *(uint4*)(u2 + pair * HH + 256 + lane * 4) = o1;
}

// ---------------------------------------------------------------------------
// Kernel 2: KT[t][h] = sum_n cr*P[n][t] - ci*Q[n][t].  2 t's per block,
// h-half per block (192 blocks); PQ loads wave-uniform, Cpk coalesced float2.
__global__ __launch_bounds__(256) void build_kt(const float2* __restrict__ Cpk,
                                                const float2* __restrict__ PQ,
                                                float* __restrict__ KT) {
    int blk = blockIdx.x;
    int t0 = (blk >> 1) * 2;
    int half = blk & 1;
    int h = half * 256 + threadIdx.x;
    float k0 = 0.0f, k1 = 0.0f;
    const float4* pq4 = (const float4*)PQ;
    int pqoff = t0 >> 1;
    #pragma unroll 8
    for (int n = 0; n < NN; ++n) {
        float2 c = Cpk[(size_t)n * HH + h];
        float4 f = pq4[(size_t)n * (TT / 2) + pqoff];   // (P[t0],Q[t0],P[t0+1],Q[t0+1])
        k0 = fmaf(c.x, f.x, k0);
        k0 = fmaf(-c.y, f.y, k0);
        k1 = fmaf(c.x, f.z, k1);
        k1 = fmaf(-c.y, f.w, k1);
    }
    KT[(size_t)t0 * HH + h] = k0;
    KT[(size_t)(t0 + 1) * HH + h] = k1;
}

// ---------------------------------------------------------------------------
// Kernel 3: pack K into step-indexed swapped half2 pairs (coalesced writes).
// KQ[s][h].x = kx = (lo K[191-2s], hi K[190-2s])   (odd-j pair)
// KQ[s][h].y = ky = (lo K[192-2s] (0 @s=0), hi K[191-2s])  (even-j pair)
__global__ void pack_k(const float* __restrict__ KT, uint2* __restrict__ KQ) {
    int idx = blockIdx.x * 256 + threadIdx.x;   // NS*HH entries
    int s = idx >> 9;
    int h = idx & 511;
    float k0 = KT[(190 - 2 * s) * HH + h];
    float k1 = KT[(191 - 2 * s) * HH + h];
    float k2 = (s == 0) ? 0.0f : KT[(192 - 2 * s) * HH + h];
    half2_t kx, ky;
    kx.x = (_Float16)k1; kx.y = (_Float16)k0;
    ky.x = (_Float16)k2; ky.y = (_Float16)k1;
    KQ[idx] = make_uint2(__builtin_bit_cast(u32, kx), __builtin_bit_cast(u32, ky));
}

// ---------------------------------------------------------------------------
// Kernel 4: causal FIR conv via v_dot2_f32_f16 + D*u residual.
// Block = 64 h x 8 l-tile waves (512 threads).  All taps for the block's 64-h
// slice staged in LDS once (48 KB): tap reads are ds_read_b64 with
// compile-time offsets, no K registers, no K ring.
// Three levers against the R3/R4 AGPR-shuttle diagnosis (one theory):
//   1. __launch_bounds__(512, 2): 256-reg budget (no pressure to demote)
//   2. fully unrolled sb sequence (no 48-wide phi set across a back-edge)
//   3. asm fdot2 with "v" constraints (class-pins acc/rings to arch VGPRs)
// Verification signal: VGPR_Count must rise to >=96.
// u: 2x16 register ring, prefetched 32 steps ahead.  u2 padded 16 rows.

template <bool PRED>
__device__ __forceinline__ u32 load_v(const u32* __restrict__ ub2, int vi) {
    int c = vi;
    if (PRED && c < 0) c = 0;
    u32 val = ub2[(size_t)c * HH];
    if (PRED && vi < 0) val = 0u;
    return val;
}

#define SLOT(p) ((p) < 16 ? W[(p)] : X[(p) - 16])

// One 16-step block; W holds v[R..R+15], X v[R+16..R+31], R = Vm1+16*sb.
// Step k: taps from LDS at (soff+k), consumes SLOT(k+m)/(k+m+1);
// if LOADU, loads v[ubase+k] into dead slot W[k].
template <bool PRED, bool LOADU>
__device__ __forceinline__ void conv_block(const u32* __restrict__ ub2,
                                           const uint2* klds,
                                           float (&acc)[LT], u32 (&W)[16], u32 (&X)[16],
                                           int ubase, int soff) {
    #pragma unroll
    for (int k = 0; k < 16; ++k) {
        u32 nv = 0u;
        if (LOADU) nv = load_v<PRED>(ub2, ubase + k);
        uint2 kq = klds[(soff + k) * 64];
        half2_t kx = __builtin_bit_cast(half2_t, kq.x);
        half2_t ky = __builtin_bit_cast(half2_t, kq.y);
        #pragma unroll
        for (int m = 0; m < 8; ++m) {
            half2_t ve = __builtin_bit_cast(half2_t, SLOT(k + m));
            half2_t vo = __builtin_bit_cast(half2_t, SLOT(k + m + 1));
            acc[2 * m]     = fdot2(ve, ky, acc[2 * m]);
            acc[2 * m + 1] = fdot2(vo, kx, acc[2 * m + 1]);
        }
        if (LOADU) W[k] = nv;
    }
}

template <bool PRED>
__device__ __forceinline__ void conv_all(const u32* __restrict__ ub2,
                                         const uint2* klds,
                                         float (&acc)[LT], u32 (&A)[16], u32 (&B)[16],
                                         int Vm1) {
    #pragma unroll
    for (int j = 0; j < 16; ++j) A[j] = load_v<PRED>(ub2, Vm1 + j);
    #pragma unroll
    for (int j = 0; j < 16; ++j) B[j] = load_v<PRED>(ub2, Vm1 + 16 + j);
    // fully unrolled sb = 0..5 (no runtime back-edge carrying the rings)
    conv_block<PRED, true >(ub2, klds, acc, A, B, Vm1 + 32, 0);    // sb0
    conv_block<PRED, true >(ub2, klds, acc, B, A, Vm1 + 48, 16);   // sb1
    conv_block<PRED, true >(ub2, klds, acc, A, B, Vm1 + 64, 32);   // sb2
    conv_block<PRED, true >(ub2, klds, acc, B, A, Vm1 + 80, 48);   // sb3
    // sb4: loads v[Vm1+96..111] = v[l0/2..l0/2+15] into A (epilogue data)
    conv_block<PRED, true >(ub2, klds, acc, A, B, Vm1 + 96, 64);
    // sb5: no loads; A preserved
    conv_block<PRED, false>(ub2, klds, acc, B, A, 0, 80);
}

__global__ __launch_bounds__(512, 2) void conv_kernel(const u32* __restrict__ u2,
                                                      const uint2* __restrict__ KQ,
                                                      const float* __restrict__ KT,
                                                      const float* __restrict__ Dp,
                                                      float* __restrict__ y) {
    __shared__ uint2 KL[NS * 64];        // 48 KB: taps for this block's 64 h's
    int tid = threadIdx.x;
    int lane = tid & 63;
    int g = tid >> 6;                    // wave = l-subtile (0..7)
    int blk = blockIdx.x;
    int hg = blk & 7;                    // 8 h-groups of 64
    int tg = (blk >> 3) & 31;            // 32 tile-groups of 8 tiles
    int b = blk >> 8;                    // 8 batches
    int h = hg * 64 + lane;
    int l0 = (tg * 8 + g) * LT;
    // cooperative K stage: NS*64 uint2 = 3072 uint4 over 512 threads
    {
        const uint2* kg = KQ + hg * 64;
        #pragma unroll
        for (int it = 0; it < (NS * 64 / 2) / 512; ++it) {
            int i = it * 512 + tid;      // uint4 index
            int s = i >> 5;
            int q = i & 31;
            uint4 v = *(const uint4*)(kg + (size_t)s * HH + q * 2);
            *(uint4*)(&KL[s * 64 + q * 2]) = v;
        }
    }
    __syncthreads();
    const u32* ub2 = u2 + (size_t)b * (LL / 2) * HH + h;
    const uint2* klds = &KL[lane];
    int Vm1 = l0 / 2 - NS;
    float acc[LT];
    u32 A[16], B[16];
    #pragma unroll
    for (int j = 0; j < LT; ++j) acc[j] = 0.0f;
    if (l0 >= TT) {
        conv_all<false>(ub2, klds, acc, A, B, Vm1);
    } else {
        conv_all<true>(ub2, klds, acc, A, B, Vm1);
    }
    float dv = Dp[h];
    float k0f = KT[h];          // K[0]
    float ce = k0f + dv;
    float* yb = y + ((size_t)b * LL + l0) * HH + h;
    // A[m] = v[l0/2+m] = (u[l0+2m], u[l0+2m+1])
    #pragma unroll
    for (int m = 0; m < 8; ++m) {
        half2_t av = __builtin_bit_cast(half2_t, A[m]);
        float ue = (float)av.x;
        float uo = (float)av.y;
        yb[(size_t)(2 * m) * HH]     = acc[2 * m] + ce * ue;
        yb[(size_t)(2 * m + 1) * HH] = acc[2 * m + 1] + dv * uo;
    }
}

// ---------------------------------------------------------------------------
extern "C" void kernel_launch(void* const* d_in, const int* in_sizes, int n_in,
                              void* d_out, int out_size, void* d_ws, size_t ws_size,
                              hipStream_t stream) {
    const float* x   = (const float*)d_in[0];
    const float* lnw = (const float*)d_in[1];
    const float* lnb = (const float*)d_in[2];
    const float* LR  = (const float*)d_in[3];
    const float* LI  = (const float*)d_in[4];
    const float* Cr  = (const float*)d_in[5];
    const float* Ci  = (const float*)d_in[6];
    const float* Dp  = (const float*)d_in[7];
    float* y  = (float*)d_out;

    float2* Cpk = (float2*)d_ws;                      // NN*HH float2   (2 MB)
    float2* PQ  = Cpk + (size_t)NN * HH;              // NN*TT float2   (0.75 MB)
    float*  KT  = (float*)(PQ + (size_t)NN * TT);     // TT*HH          (384 KB)
    uint2*  KQ  = (uint2*)(KT + (size_t)TT * HH);     // NS*HH uint2    (384 KB)
    u32*    u2  = (u32*)(KQ + (size_t)NS * HH);       // BB*(LL/2)*HH + 16-row pad

    prep_kernel<<<LN_BLKS + 64 + NN, 256, 0, stream>>>(x, lnw, lnb, Cr, Ci,
                                                       LR, LI, u2, Cpk, PQ);
    build_kt<<<TT, 256, 0, stream>>>(Cpk, PQ, KT);
    pack_k<<<NS * HH / 256, 256, 0, stream>>>(KT, KQ);
    conv_kernel<<<BB * (LL / (8 * LT)) * 8, 512, 0, stream>>>(u2, KQ, KT, Dp, y);
}

// Round 9
// 219.385 us; speedup vs baseline: 1.1279x; 1.1100x over previous
//
#include <hip/hip_runtime.h>
#include <math.h>

#define BB 8
#define LL 4096
#define HH 512
#define NN 512
#define TT 192        // truncated FIR length
#define NS 96         // tap-pair steps (TT/2)
#define LT 8          // output rows per wave tile (R9: 16->8, smaller live set)

typedef _Float16 half2_t __attribute__((ext_vector_type(2)));
typedef unsigned int u32;
typedef unsigned short u16;

#if __has_builtin(__builtin_amdgcn_fdot2)
__device__ __forceinline__ float fdot2(half2_t a, half2_t b, float c) {
    return __builtin_amdgcn_fdot2(a, b, c, false);
}
#else
__device__ __forceinline__ float fdot2(half2_t a, half2_t b, float c) {
    return c + (float)a.x * (float)b.x + (float)a.y * (float)b.y;
}
#endif

// ---------------------------------------------------------------------------
// Kernel 1 (fused prep), 3 branches by blockIdx:
//   [0, 4096)     : LayerNorm + fp16 pack of adjacent L-row pairs
//   [4096, 4160)  : transpose+pack C [H,N] -> Cpk[N,H] float2(cr,ci)
//   [4160, 4672)  : PQ[n][t] = float2(Re(s_n w_n^t), Im(s_n w_n^t))
#define LN_BLKS (BB * LL / 8)
__global__ __launch_bounds__(256) void prep_kernel(const float* __restrict__ x,
                                                   const float* __restrict__ w,
                                                   const float* __restrict__ bia,
                                                   const float* __restrict__ Cr,
                                                   const float* __restrict__ Ci,
                                                   const float* __restrict__ LR,
                                                   const float* __restrict__ LI,
                                                   u32* __restrict__ u2,
                                                   float2* __restrict__ Cpk,
                                                   float2* __restrict__ PQ) {
    __shared__ float tile[64][65];
    if (blockIdx.x >= LN_BLKS + 64) {
        // ---- PQ branch: one n per block, t = tid (192 of 256 active) ----
        int n = blockIdx.x - (LN_BLKS + 64);
        int t = threadIdx.x;
        if (t < TT) {
            float lr = -expf(LR[n]);
            float li = expf(LI[n]);
            float el = expf(lr);
            float sn, cs;
            sincosf(li, &sn, &cs);
            float nr = el * cs - 1.0f;
            float ni = el * sn;
            float inv = 1.0f / (lr * lr + li * li);
            float sr = (nr * lr + ni * li) * inv;   // s = (e^lam-1)/lam
            float si = (ni * lr - nr * li) * inv;
            float tf = (float)t;
            float e2 = expf(lr * tf);
            float s2, c2;
            sincosf(li * tf, &s2, &c2);
            float er = e2 * c2, ei = e2 * s2;       // w^t
            PQ[(size_t)n * TT + t] = make_float2(sr * er - si * ei, sr * ei + si * er);
        }
        return;
    }
    if (blockIdx.x >= LN_BLKS) {
        // ---- transpose+pack branch: single tile, R then I ----
        int tb = blockIdx.x - LN_BLKS;   // 0..63
        int h0 = (tb & 7) * 64;
        int n0 = (tb >> 3) * 64;
        int c = threadIdx.x & 63;
        int r0 = threadIdx.x >> 6;
        float vr[16], vi[16];
        #pragma unroll
        for (int i = 0; i < 16; ++i) {
            int r = r0 + i * 4;
            tile[r][c] = Cr[(size_t)(h0 + r) * NN + n0 + c];
        }
        __syncthreads();
        #pragma unroll
        for (int i = 0; i < 16; ++i) vr[i] = tile[c][r0 + i * 4];
        __syncthreads();
        #pragma unroll
        for (int i = 0; i < 16; ++i) {
            int r = r0 + i * 4;
            tile[r][c] = Ci[(size_t)(h0 + r) * NN + n0 + c];
        }
        __syncthreads();
        #pragma unroll
        for (int i = 0; i < 16; ++i) vi[i] = tile[c][r0 + i * 4];
        #pragma unroll
        for (int i = 0; i < 16; ++i) {
            int r = r0 + i * 4;
            Cpk[(size_t)(n0 + r) * HH + h0 + c] = make_float2(vr[i], vi[i]);
        }
        return;
    }
    // ---- layernorm branch: one wave per L-row pair ----
    int wave = threadIdx.x >> 6;
    int lane = threadIdx.x & 63;
    size_t pair = (size_t)blockIdx.x * 4 + wave;
    const float* xr0 = x + pair * 2 * HH;
    const float* xr1 = xr0 + HH;
    float4 a0 = *(const float4*)(xr0 + lane * 4);
    float4 a1 = *(const float4*)(xr0 + 256 + lane * 4);
    float4 b0 = *(const float4*)(xr1 + lane * 4);
    float4 b1 = *(const float4*)(xr1 + 256 + lane * 4);
    float sA  = a0.x + a0.y + a0.z + a0.w + a1.x + a1.y + a1.z + a1.w;
    float qA  = a0.x*a0.x + a0.y*a0.y + a0.z*a0.z + a0.w*a0.w
              + a1.x*a1.x + a1.y*a1.y + a1.z*a1.z + a1.w*a1.w;
    float sB  = b0.x + b0.y + b0.z + b0.w + b1.x + b1.y + b1.z + b1.w;
    float qB  = b0.x*b0.x + b0.y*b0.y + b0.z*b0.z + b0.w*b0.w
              + b1.x*b1.x + b1.y*b1.y + b1.z*b1.z + b1.w*b1.w;
    #pragma unroll
    for (int off = 1; off < 64; off <<= 1) {
        sA += __shfl_xor(sA, off, 64);
        qA += __shfl_xor(qA, off, 64);
        sB += __shfl_xor(sB, off, 64);
        qB += __shfl_xor(qB, off, 64);
    }
    float mA = sA * (1.0f / 512.0f);
    float rA = rsqrtf(qA * (1.0f / 512.0f) - mA * mA + 1e-5f);
    float mB = sB * (1.0f / 512.0f);
    float rB = rsqrtf(qB * (1.0f / 512.0f) - mB * mB + 1e-5f);
    float4 w0 = *(const float4*)(w + lane * 4);
    float4 w1 = *(const float4*)(w + 256 + lane * 4);
    float4 c0 = *(const float4*)(bia + lane * 4);
    float4 c1 = *(const float4*)(bia + 256 + lane * 4);
    uint4 o0, o1;
    {
        half2_t p;
        p.x = (_Float16)((a0.x - mA) * rA * w0.x + c0.x);
        p.y = (_Float16)((b0.x - mB) * rB * w0.x + c0.x);
        o0.x = __builtin_bit_cast(u32, p);
        p.x = (_Float16)((a0.y - mA) * rA * w0.y + c0.y);
        p.y = (_Float16)((b0.y - mB) * rB * w0.y + c0.y);
        o0.y = __builtin_bit_cast(u32, p);
        p.x = (_Float16)((a0.z - mA) * rA * w0.z + c0.z);
        p.y = (_Float16)((b0.z - mB) * rB * w0.z + c0.z);
        o0.z = __builtin_bit_cast(u32, p);
        p.x = (_Float16)((a0.w - mA) * rA * w0.w + c0.w);
        p.y = (_Float16)((b0.w - mB) * rB * w0.w + c0.w);
        o0.w = __builtin_bit_cast(u32, p);
        p.x = (_Float16)((a1.x - mA) * rA * w1.x + c1.x);
        p.y = (_Float16)((b1.x - mB) * rB * w1.x + c1.x);
        o1.x = __builtin_bit_cast(u32, p);
        p.x = (_Float16)((a1.y - mA) * rA * w1.y + c1.y);
        p.y = (_Float16)((b1.y - mB) * rB * w1.y + c1.y);
        o1.y = __builtin_bit_cast(u32, p);
        p.x = (_Float16)((a1.z - mA) * rA * w1.z + c1.z);
        p.y = (_Float16)((b1.z - mB) * rB * w1.z + c1.z);
        o1.z = __builtin_bit_cast(u32, p);
        p.x = (_Float16)((a1.w - mA) * rA * w1.w + c1.w);
        p.y = (_Float16)((b1.w - mB) * rB * w1.w + c1.w);
        o1.w = __builtin_bit_cast(u32, p);
    }
    *(uint4*)(u2 + pair * HH + lane * 4) = o0;
    *(uint4*)(u2 + pair * HH + 256 + lane * 4) = o1;
}

// ---------------------------------------------------------------------------
// Kernel 2: KT[t][h] = sum_n cr*P[n][t] - ci*Q[n][t].
// R9: 512 threads/block, n-range split across two 256-thread halves +
// LDS reduce.  Old version: 192 blocks x 256 thr = 0.75 blocks/CU (half the
// GPU idle, latency-bound).  Now 2x waves per block.
__global__ __launch_bounds__(512) void build_kt(const float2* __restrict__ Cpk,
                                                const float2* __restrict__ PQ,
                                                float* __restrict__ KT) {
    __shared__ float red[256][2];
    int blk = blockIdx.x;
    int t0 = (blk >> 1) * 2;
    int half = blk & 1;
    int hh = threadIdx.x & 255;
    int nh = threadIdx.x >> 8;          // 0 or 1: n-range half
    int h = half * 256 + hh;
    float k0 = 0.0f, k1 = 0.0f;
    const float4* pq4 = (const float4*)PQ;
    int pqoff = t0 >> 1;
    int n0 = nh * 256;
    #pragma unroll 8
    for (int n = n0; n < n0 + 256; ++n) {
        float2 c = Cpk[(size_t)n * HH + h];
        float4 f = pq4[(size_t)n * (TT / 2) + pqoff];   // (P[t0],Q[t0],P[t0+1],Q[t0+1])
        k0 = fmaf(c.x, f.x, k0);
        k0 = fmaf(-c.y, f.y, k0);
        k1 = fmaf(c.x, f.z, k1);
        k1 = fmaf(-c.y, f.w, k1);
    }
    if (nh) { red[hh][0] = k0; red[hh][1] = k1; }
    __syncthreads();
    if (!nh) {
        k0 += red[hh][0];
        k1 += red[hh][1];
        KT[(size_t)t0 * HH + h] = k0;
        KT[(size_t)(t0 + 1) * HH + h] = k1;
    }
}

// ---------------------------------------------------------------------------
// Kernel 3: pack K into step-indexed swapped half2 pairs (coalesced writes).
// KQ[s][h].x = kx = (lo K[191-2s], hi K[190-2s])   (odd-j pair)
// KQ[s][h].y = ky = (lo K[192-2s] (0 @s=0), hi K[191-2s])  (even-j pair)
__global__ void pack_k(const float* __restrict__ KT, uint2* __restrict__ KQ) {
    int idx = blockIdx.x * 256 + threadIdx.x;   // NS*HH entries
    int s = idx >> 9;
    int h = idx & 511;
    float k0 = KT[(190 - 2 * s) * HH + h];
    float k1 = KT[(191 - 2 * s) * HH + h];
    float k2 = (s == 0) ? 0.0f : KT[(192 - 2 * s) * HH + h];
    half2_t kx, ky;
    kx.x = (_Float16)k1; kx.y = (_Float16)k0;
    ky.x = (_Float16)k2; ky.y = (_Float16)k1;
    KQ[idx] = make_uint2(__builtin_bit_cast(u32, kx), __builtin_bit_cast(u32, ky));
}

// ---------------------------------------------------------------------------
// Kernel 4 (R9 restructure): causal FIR conv via v_dot2_f32_f16 + D*u.
// Block = 64 h x 8 l-tile waves (512 thr); each wave produces LT=8 rows.
// Taps staged in LDS once (48 KB) as before.
// u-ring: single 24-slot circular ring, ALL indices compile-time under the
// full 96-step unroll ((s+m)%24 with s,m constants -> no scratch, rule #20).
// Loads issued at step s land in slot s%24 and are consumed 19+ steps later
// -> natural load-early/use-late distance for the scheduler.
// R3-R8 lesson: the LT=16 2x16-ring + 16 acc (~48 long-lived values) was
// AGPR-demoted by the allocator (~170 unified regs/wave -> 3 waves/SIMD,
// VALUBusy 68%); three source-level hints failed to stop it.  This version
// shrinks the core live set to ~36 (8 acc + 24 ring + temps) so demotion
// has nothing to chew on.  Target: 4-6 waves/SIMD (LDS caps at 6).

template <bool PRED>
__device__ __forceinline__ u32 load_v(const u32* __restrict__ ub2, int vi) {
    int c = vi;
    if (PRED && c < 0) c = 0;
    u32 val = ub2[(size_t)c * HH];
    if (PRED && vi < 0) val = 0u;
    return val;
}

// Invariant at start of step s: W[(s+i)%24] = v[Vm1+s+i], i=0..23.
// Step s consumes slots s..s+4 (mod 24); if s<76 loads v[Vm1+s+24] into
// slot s%24 (dead after this step's m=0 use).  After step 95, W[0..3] =
// v[Vm1+96..99] = v[l0/2..l0/2+3] (epilogue u values).
template <bool PRED>
__device__ __forceinline__ void conv96(const u32* __restrict__ ub2,
                                       const uint2* klds,
                                       float (&acc)[LT], u32 (&W)[24],
                                       int Vm1) {
    #pragma unroll
    for (int i = 0; i < 24; ++i) W[i] = load_v<PRED>(ub2, Vm1 + i);
    #pragma unroll
    for (int s = 0; s < 96; ++s) {
        u32 nv = 0u;
        if (s < 76) nv = load_v<PRED>(ub2, Vm1 + s + 24);
        uint2 kq = klds[s * 64];
        half2_t kx = __builtin_bit_cast(half2_t, kq.x);
        half2_t ky = __builtin_bit_cast(half2_t, kq.y);
        #pragma unroll
        for (int m = 0; m < 4; ++m) {
            half2_t ve = __builtin_bit_cast(half2_t, W[(s + m) % 24]);
            half2_t vo = __builtin_bit_cast(half2_t, W[(s + m + 1) % 24]);
            acc[2 * m]     = fdot2(ve, ky, acc[2 * m]);
            acc[2 * m + 1] = fdot2(vo, kx, acc[2 * m + 1]);
        }
        if (s < 76) W[s % 24] = nv;
    }
}

__global__ __launch_bounds__(512, 4) void conv_kernel(const u32* __restrict__ u2,
                                                      const uint2* __restrict__ KQ,
                                                      const float* __restrict__ KT,
                                                      const float* __restrict__ Dp,
                                                      float* __restrict__ y) {
    __shared__ uint2 KL[NS * 64];        // 48 KB: taps for this block's 64 h's
    int tid = threadIdx.x;
    int lane = tid & 63;
    int g = tid >> 6;                    // wave = l-subtile (0..7)
    int blk = blockIdx.x;
    int hg = blk & 7;                    // 8 h-groups of 64
    int tg = (blk >> 3) & 63;            // 64 tile-groups of 8 tiles
    int b = blk >> 9;                    // 8 batches
    int h = hg * 64 + lane;
    int l0 = (tg * 8 + g) * LT;
    // cooperative K stage: NS*64 uint2 = 3072 uint4 over 512 threads
    {
        const uint2* kg = KQ + hg * 64;
        #pragma unroll
        for (int it = 0; it < (NS * 64 / 2) / 512; ++it) {
            int i = it * 512 + tid;      // uint4 index
            int s = i >> 5;
            int q = i & 31;
            uint4 v = *(const uint4*)(kg + (size_t)s * HH + q * 2);
            *(uint4*)(&KL[s * 64 + q * 2]) = v;
        }
    }
    __syncthreads();
    const u32* ub2 = u2 + (size_t)b * (LL / 2) * HH + h;
    const uint2* klds = &KL[lane];
    int Vm1 = l0 / 2 - NS;
    float acc[LT];
    u32 W[24];
    #pragma unroll
    for (int j = 0; j < LT; ++j) acc[j] = 0.0f;
    if (l0 >= TT) {
        conv96<false>(ub2, klds, acc, W, Vm1);
    } else {
        conv96<true>(ub2, klds, acc, W, Vm1);
    }
    float dv = Dp[h];
    float k0f = KT[h];          // K[0]
    float ce = k0f + dv;
    float* yb = y + ((size_t)b * LL + l0) * HH + h;
    // W[m] = v[l0/2+m] = (u[l0+2m], u[l0+2m+1]), m=0..3
    #pragma unroll
    for (int m = 0; m < 4; ++m) {
        half2_t av = __builtin_bit_cast(half2_t, W[m]);
        float ue = (float)av.x;
        float uo = (float)av.y;
        yb[(size_t)(2 * m) * HH]     = acc[2 * m] + ce * ue;
        yb[(size_t)(2 * m + 1) * HH] = acc[2 * m + 1] + dv * uo;
    }
}

// ---------------------------------------------------------------------------
extern "C" void kernel_launch(void* const* d_in, const int* in_sizes, int n_in,
                              void* d_out, int out_size, void* d_ws, size_t ws_size,
                              hipStream_t stream) {
    const float* x   = (const float*)d_in[0];
    const float* lnw = (const float*)d_in[1];
    const float* lnb = (const float*)d_in[2];
    const float* LR  = (const float*)d_in[3];
    const float* LI  = (const float*)d_in[4];
    const float* Cr  = (const float*)d_in[5];
    const float* Ci  = (const float*)d_in[6];
    const float* Dp  = (const float*)d_in[7];
    float* y  = (float*)d_out;

    float2* Cpk = (float2*)d_ws;                      // NN*HH float2   (2 MB)
    float2* PQ  = Cpk + (size_t)NN * HH;              // NN*TT float2   (0.75 MB)
    float*  KT  = (float*)(PQ + (size_t)NN * TT);     // TT*HH          (384 KB)
    uint2*  KQ  = (uint2*)(KT + (size_t)TT * HH);     // NS*HH uint2    (384 KB)
    u32*    u2  = (u32*)(KQ + (size_t)NS * HH);       // BB*(LL/2)*HH + 16-row pad

    prep_kernel<<<LN_BLKS + 64 + NN, 256, 0, stream>>>(x, lnw, lnb, Cr, Ci,
                                                       LR, LI, u2, Cpk, PQ);
    build_kt<<<TT, 512, 0, stream>>>(Cpk, PQ, KT);
    pack_k<<<NS * HH / 256, 256, 0, stream>>>(KT, KQ);
    conv_kernel<<<BB * (LL / (8 * LT)) * 8, 512, 0, stream>>>(u2, KQ, KT, Dp, y);
}

// Round 13
// 211.871 us; speedup vs baseline: 1.1679x; 1.0355x over previous
//
#include <hip/hip_runtime.h>
#include <math.h>

#define BB 8
#define LL 4096
#define HH 512
#define NN 512
#define TT 192        // truncated FIR length
#define NS 96         // tap-pair steps (TT/2)
#define LT 16         // output rows per wave tile (R10: revert to 16 - R9's LT=8 regressed conv 71->85us)

typedef _Float16 half2_t __attribute__((ext_vector_type(2)));
typedef unsigned int u32;
typedef unsigned short u16;

// R8-measured best conv config: asm fdot2 ("v"-pinned), 71.4us.
#if defined(__AMDGCN__)
__device__ __forceinline__ float fdot2(half2_t a, half2_t b, float c) {
    asm("v_dot2_f32_f16 %0, %1, %2, %0" : "+v"(c) : "v"(a), "v"(b));
    return c;
}
#elif __has_builtin(__builtin_amdgcn_fdot2)
__device__ __forceinline__ float fdot2(half2_t a, half2_t b, float c) {
    return __builtin_amdgcn_fdot2(a, b, c, false);
}
#else
__device__ __forceinline__ float fdot2(half2_t a, half2_t b, float c) {
    return c + (float)a.x * (float)b.x + (float)a.y * (float)b.y;
}
#endif

// ---------------------------------------------------------------------------
// Kernel 1 (fused prep), 3 branches by blockIdx:
//   [0, 4096)     : LayerNorm + fp16 pack of adjacent L-row pairs
//   [4096, 4160)  : transpose+pack C [H,N] -> Cpk[N,H] float2(cr,ci)
//   [4160, 4672)  : PQ[n][t] = float2(Re(s_n w_n^t), Im(s_n w_n^t))
#define LN_BLKS (BB * LL / 8)
__global__ __launch_bounds__(256) void prep_kernel(const float* __restrict__ x,
                                                   const float* __restrict__ w,
                                                   const float* __restrict__ bia,
                                                   const float* __restrict__ Cr,
                                                   const float* __restrict__ Ci,
                                                   const float* __restrict__ LR,
                                                   const float* __restrict__ LI,
                                                   u32* __restrict__ u2,
                                                   float2* __restrict__ Cpk,
                                                   float2* __restrict__ PQ) {
    __shared__ float tile[64][65];
    if (blockIdx.x >= LN_BLKS + 64) {
        // ---- PQ branch: one n per block, t = tid (192 of 256 active) ----
        int n = blockIdx.x - (LN_BLKS + 64);
        int t = threadIdx.x;
        if (t < TT) {
            float lr = -expf(LR[n]);
            float li = expf(LI[n]);
            float el = expf(lr);
            float sn, cs;
            sincosf(li, &sn, &cs);
            float nr = el * cs - 1.0f;
            float ni = el * sn;
            float inv = 1.0f / (lr * lr + li * li);
            float sr = (nr * lr + ni * li) * inv;   // s = (e^lam-1)/lam
            float si = (ni * lr - nr * li) * inv;
            float tf = (float)t;
            float e2 = expf(lr * tf);
            float s2, c2;
            sincosf(li * tf, &s2, &c2);
            float er = e2 * c2, ei = e2 * s2;       // w^t
            PQ[(size_t)n * TT + t] = make_float2(sr * er - si * ei, sr * ei + si * er);
        }
        return;
    }
    if (blockIdx.x >= LN_BLKS) {
        // ---- transpose+pack branch: single tile, R then I ----
        int tb = blockIdx.x - LN_BLKS;   // 0..63
        int h0 = (tb & 7) * 64;
        int n0 = (tb >> 3) * 64;
        int c = threadIdx.x & 63;
        int r0 = threadIdx.x >> 6;
        float vr[16], vi[16];
        #pragma unroll
        for (int i = 0; i < 16; ++i) {
            int r = r0 + i * 4;
            tile[r][c] = Cr[(size_t)(h0 + r) * NN + n0 + c];
        }
        __syncthreads();
        #pragma unroll
        for (int i = 0; i < 16; ++i) vr[i] = tile[c][r0 + i * 4];
        __syncthreads();
        #pragma unroll
        for (int i = 0; i < 16; ++i) {
            int r = r0 + i * 4;
            tile[r][c] = Ci[(size_t)(h0 + r) * NN + n0 + c];
        }
        __syncthreads();
        #pragma unroll
        for (int i = 0; i < 16; ++i) vi[i] = tile[c][r0 + i * 4];
        #pragma unroll
        for (int i = 0; i < 16; ++i) {
            int r = r0 + i * 4;
            Cpk[(size_t)(n0 + r) * HH + h0 + c] = make_float2(vr[i], vi[i]);
        }
        return;
    }
    // ---- layernorm branch: one wave per L-row pair ----
    int wave = threadIdx.x >> 6;
    int lane = threadIdx.x & 63;
    size_t pair = (size_t)blockIdx.x * 4 + wave;
    const float* xr0 = x + pair * 2 * HH;
    const float* xr1 = xr0 + HH;
    float4 a0 = *(const float4*)(xr0 + lane * 4);
    float4 a1 = *(const float4*)(xr0 + 256 + lane * 4);
    float4 b0 = *(const float4*)(xr1 + lane * 4);
    float4 b1 = *(const float4*)(xr1 + 256 + lane * 4);
    float sA  = a0.x + a0.y + a0.z + a0.w + a1.x + a1.y + a1.z + a1.w;
    float qA  = a0.x*a0.x + a0.y*a0.y + a0.z*a0.z + a0.w*a0.w
              + a1.x*a1.x + a1.y*a1.y + a1.z*a1.z + a1.w*a1.w;
    float sB  = b0.x + b0.y + b0.z + b0.w + b1.x + b1.y + b1.z + b1.w;
    float qB  = b0.x*b0.x + b0.y*b0.y + b0.z*b0.z + b0.w*b0.w
              + b1.x*b1.x + b1.y*b1.y + b1.z*b1.z + b1.w*b1.w;
    #pragma unroll
    for (int off = 1; off < 64; off <<= 1) {
        sA += __shfl_xor(sA, off, 64);
        qA += __shfl_xor(qA, off, 64);
        sB += __shfl_xor(sB, off, 64);
        qB += __shfl_xor(qB, off, 64);
    }
    float mA = sA * (1.0f / 512.0f);
    float rA = rsqrtf(qA * (1.0f / 512.0f) - mA * mA + 1e-5f);
    float mB = sB * (1.0f / 512.0f);
    float rB = rsqrtf(qB * (1.0f / 512.0f) - mB * mB + 1e-5f);
    float4 w0 = *(const float4*)(w + lane * 4);
    float4 w1 = *(const float4*)(w + 256 + lane * 4);
    float4 c0 = *(const float4*)(bia + lane * 4);
    float4 c1 = *(const float4*)(bia + 256 + lane * 4);
    uint4 o0, o1;
    {
        half2_t p;
        p.x = (_Float16)((a0.x - mA) * rA * w0.x + c0.x);
        p.y = (_Float16)((b0.x - mB) * rB * w0.x + c0.x);
        o0.x = __builtin_bit_cast(u32, p);
        p.x = (_Float16)((a0.y - mA) * rA * w0.y + c0.y);
        p.y = (_Float16)((b0.y - mB) * rB * w0.y + c0.y);
        o0.y = __builtin_bit_cast(u32, p);
        p.x = (_Float16)((a0.z - mA) * rA * w0.z + c0.z);
        p.y = (_Float16)((b0.z - mB) * rB * w0.z + c0.z);
        o0.z = __builtin_bit_cast(u32, p);
        p.x = (_Float16)((a0.w - mA) * rA * w0.w + c0.w);
        p.y = (_Float16)((b0.w - mB) * rB * w0.w + c0.w);
        o0.w = __builtin_bit_cast(u32, p);
        p.x = (_Float16)((a1.x - mA) * rA * w1.x + c1.x);
        p.y = (_Float16)((b1.x - mB) * rB * w1.x + c1.x);
        o1.x = __builtin_bit_cast(u32, p);
        p.x = (_Float16)((a1.y - mA) * rA * w1.y + c1.y);
        p.y = (_Float16)((b1.y - mB) * rB * w1.y + c1.y);
        o1.y = __builtin_bit_cast(u32, p);
        p.x = (_Float16)((a1.z - mA) * rA * w1.z + c1.z);
        p.y = (_Float16)((b1.z - mB) * rB * w1.z + c1.z);
        o1.z = __builtin_bit_cast(u32, p);
        p.x = (_Float16)((a1.w - mA) * rA * w1.w + c1.w);
        p.y = (_Float16)((b1.w - mB) * rB * w1.w + c1.w);
        o1.w = __builtin_bit_cast(u32, p);
    }
    *(uint4*)(u2 + pair * HH + lane * 4) = o0;
    *(uint4*)(u2 + pair * HH + 256 + lane * 4) = o1;
}

// ---------------------------------------------------------------------------
// Kernel 2 (R10): KT[t][h] = sum_n cr*P[n][t] - ci*Q[n][t].
// R9 post-mortem: build_kt was ~74us latency-bound at 192x256 (0.75 blk/CU);
// 2x parallelism (R9) -> ~37us (saved 37 of total).  R10: 4x more TLP:
// 384 blocks (96 t-pairs x 4 h-quarters) x 512 thr, 4-way n-split + LDS
// reduce; 128 iters/thread, 3KB LDS.
__global__ __launch_bounds__(512) void build_kt(const float2* __restrict__ Cpk,
                                                const float2* __restrict__ PQ,
                                                float* __restrict__ KT) {
    __shared__ float red[3][128][2];
    int blk = blockIdx.x;               // 96 t-pairs * 4 h-quarters
    int t0 = (blk >> 2) * 2;
    int hq = blk & 3;
    int hh = threadIdx.x & 127;
    int nq = threadIdx.x >> 7;          // 0..3: n-quarter (wave-uniform)
    int h = hq * 128 + hh;
    float k0 = 0.0f, k1 = 0.0f;
    const float4* pq4 = (const float4*)PQ;
    int pqoff = t0 >> 1;
    int n0 = nq * 128;
    #pragma unroll 8
    for (int n = n0; n < n0 + 128; ++n) {
        float2 c = Cpk[(size_t)n * HH + h];
        float4 f = pq4[(size_t)n * (TT / 2) + pqoff];   // (P[t0],Q[t0],P[t0+1],Q[t0+1])
        k0 = fmaf(c.x, f.x, k0);
        k0 = fmaf(-c.y, f.y, k0);
        k1 = fmaf(c.x, f.z, k1);
        k1 = fmaf(-c.y, f.w, k1);
    }
    if (nq) { red[nq - 1][hh][0] = k0; red[nq - 1][hh][1] = k1; }
    __syncthreads();
    if (nq == 0) {
        #pragma unroll
        for (int i = 0; i < 3; ++i) { k0 += red[i][hh][0]; k1 += red[i][hh][1]; }
        KT[(size_t)t0 * HH + h] = k0;
        KT[(size_t)(t0 + 1) * HH + h] = k1;
    }
}

// ---------------------------------------------------------------------------
// Kernel 3: pack K into step-indexed swapped half2 pairs (coalesced writes).
// KQ[s][h].x = kx = (lo K[191-2s], hi K[190-2s])   (odd-j pair)
// KQ[s][h].y = ky = (lo K[192-2s] (0 @s=0), hi K[191-2s])  (even-j pair)
__global__ void pack_k(const float* __restrict__ KT, uint2* __restrict__ KQ) {
    int idx = blockIdx.x * 256 + threadIdx.x;   // NS*HH entries
    int s = idx >> 9;
    int h = idx & 511;
    float k0 = KT[(190 - 2 * s) * HH + h];
    float k1 = KT[(191 - 2 * s) * HH + h];
    float k2 = (s == 0) ? 0.0f : KT[(192 - 2 * s) * HH + h];
    half2_t kx, ky;
    kx.x = (_Float16)k1; kx.y = (_Float16)k0;
    ky.x = (_Float16)k2; ky.y = (_Float16)k1;
    KQ[idx] = make_uint2(__builtin_bit_cast(u32, kx), __builtin_bit_cast(u32, ky));
}

// ---------------------------------------------------------------------------
// Kernel 4: causal FIR conv via v_dot2_f32_f16 + D*u residual.
// EXACT R8 configuration (measured 71.4us, best so far): LT=16, 2x16 u-ring,
// asm fdot2, __launch_bounds__(512,2), fully unrolled sb sequence.
// R9's LT=8 experiment: occupancy 38->49% but conv 71->85us (overhead/wave
// ~flat while waves doubled) => occupancy is NOT the binding constraint;
// per-wave overhead amortization (big LT) matters more.

template <bool PRED>
__device__ __forceinline__ u32 load_v(const u32* __restrict__ ub2, int vi) {
    int c = vi;
    if (PRED && c < 0) c = 0;
    u32 val = ub2[(size_t)c * HH];
    if (PRED && vi < 0) val = 0u;
    return val;
}

#define SLOT(p) ((p) < 16 ? W[(p)] : X[(p) - 16])

// One 16-step block; W holds v[R..R+15], X v[R+16..R+31], R = Vm1+16*sb.
// Step k: taps from LDS at (soff+k), consumes SLOT(k+m)/(k+m+1);
// if LOADU, loads v[ubase+k] into dead slot W[k].
template <bool PRED, bool LOADU>
__device__ __forceinline__ void conv_block(const u32* __restrict__ ub2,
                                           const uint2* klds,
                                           float (&acc)[LT], u32 (&W)[16], u32 (&X)[16],
                                           int ubase, int soff) {
    #pragma unroll
    for (int k = 0; k < 16; ++k) {
        u32 nv = 0u;
        if (LOADU) nv = load_v<PRED>(ub2, ubase + k);
        uint2 kq = klds[(soff + k) * 64];
        half2_t kx = __builtin_bit_cast(half2_t, kq.x);
        half2_t ky = __builtin_bit_cast(half2_t, kq.y);
        #pragma unroll
        for (int m = 0; m < 8; ++m) {
            half2_t ve = __builtin_bit_cast(half2_t, SLOT(k + m));
            half2_t vo = __builtin_bit_cast(half2_t, SLOT(k + m + 1));
            acc[2 * m]     = fdot2(ve, ky, acc[2 * m]);
            acc[2 * m + 1] = fdot2(vo, kx, acc[2 * m + 1]);
        }
        if (LOADU) W[k] = nv;
    }
}

template <bool PRED>
__device__ __forceinline__ void conv_all(const u32* __restrict__ ub2,
                                         const uint2* klds,
                                         float (&acc)[LT], u32 (&A)[16], u32 (&B)[16],
                                         int Vm1) {
    #pragma unroll
    for (int j = 0; j < 16; ++j) A[j] = load_v<PRED>(ub2, Vm1 + j);
    #pragma unroll
    for (int j = 0; j < 16; ++j) B[j] = load_v<PRED>(ub2, Vm1 + 16 + j);
    // fully unrolled sb = 0..5 (no runtime back-edge carrying the rings)
    conv_block<PRED, true >(ub2, klds, acc, A, B, Vm1 + 32, 0);    // sb0
    conv_block<PRED, true >(ub2, klds, acc, B, A, Vm1 + 48, 16);   // sb1
    conv_block<PRED, true >(ub2, klds, acc, A, B, Vm1 + 64, 32);   // sb2
    conv_block<PRED, true >(ub2, klds, acc, B, A, Vm1 + 80, 48);   // sb3
    // sb4: loads v[Vm1+96..111] = v[l0/2..l0/2+15] into A (epilogue data)
    conv_block<PRED, true >(ub2, klds, acc, A, B, Vm1 + 96, 64);
    // sb5: no loads; A preserved
    conv_block<PRED, false>(ub2, klds, acc, B, A, 0, 80);
}

__global__ __launch_bounds__(512, 2) void conv_kernel(const u32* __restrict__ u2,
                                                      const uint2* __restrict__ KQ,
                                                      const float* __restrict__ KT,
                                                      const float* __restrict__ Dp,
                                                      float* __restrict__ y) {
    __shared__ uint2 KL[NS * 64];        // 48 KB: taps for this block's 64 h's
    int tid = threadIdx.x;
    int lane = tid & 63;
    int g = tid >> 6;                    // wave = l-subtile (0..7)
    int blk = blockIdx.x;
    int hg = blk & 7;                    // 8 h-groups of 64
    int tg = (blk >> 3) & 31;            // 32 tile-groups of 8 tiles
    int b = blk >> 8;                    // 8 batches
    int h = hg * 64 + lane;
    int l0 = (tg * 8 + g) * LT;
    // cooperative K stage: NS*64 uint2 = 3072 uint4 over 512 threads
    {
        const uint2* kg = KQ + hg * 64;
        #pragma unroll
        for (int it = 0; it < (NS * 64 / 2) / 512; ++it) {
            int i = it * 512 + tid;      // uint4 index
            int s = i >> 5;
            int q = i & 31;
            uint4 v = *(const uint4*)(kg + (size_t)s * HH + q * 2);
            *(uint4*)(&KL[s * 64 + q * 2]) = v;
        }
    }
    __syncthreads();
    const u32* ub2 = u2 + (size_t)b * (LL / 2) * HH + h;
    const uint2* klds = &KL[lane];
    int Vm1 = l0 / 2 - NS;
    float acc[LT];
    u32 A[16], B[16];
    #pragma unroll
    for (int j = 0; j < LT; ++j) acc[j] = 0.0f;
    if (l0 >= TT) {
        conv_all<false>(ub2, klds, acc, A, B, Vm1);
    } else {
        conv_all<true>(ub2, klds, acc, A, B, Vm1);
    }
    float dv = Dp[h];
    float k0f = KT[h];          // K[0]
    float ce = k0f + dv;
    float* yb = y + ((size_t)b * LL + l0) * HH + h;
    // A[m] = v[l0/2+m] = (u[l0+2m], u[l0+2m+1])
    #pragma unroll
    for (int m = 0; m < 8; ++m) {
        half2_t av = __builtin_bit_cast(half2_t, A[m]);
        float ue = (float)av.x;
        float uo = (float)av.y;
        yb[(size_t)(2 * m) * HH]     = acc[2 * m] + ce * ue;
        yb[(size_t)(2 * m + 1) * HH] = acc[2 * m + 1] + dv * uo;
    }
}

// ---------------------------------------------------------------------------
extern "C" void kernel_launch(void* const* d_in, const int* in_sizes, int n_in,
                              void* d_out, int out_size, void* d_ws, size_t ws_size,
                              hipStream_t stream) {
    const float* x   = (const float*)d_in[0];
    const float* lnw = (const float*)d_in[1];
    const float* lnb = (const float*)d_in[2];
    const float* LR  = (const float*)d_in[3];
    const float* LI  = (const float*)d_in[4];
    const float* Cr  = (const float*)d_in[5];
    const float* Ci  = (const float*)d_in[6];
    const float* Dp  = (const float*)d_in[7];
    float* y  = (float*)d_out;

    float2* Cpk = (float2*)d_ws;                      // NN*HH float2   (2 MB)
    float2* PQ  = Cpk + (size_t)NN * HH;              // NN*TT float2   (0.75 MB)
    float*  KT  = (float*)(PQ + (size_t)NN * TT);     // TT*HH          (384 KB)
    uint2*  KQ  = (uint2*)(KT + (size_t)TT * HH);     // NS*HH uint2    (384 KB)
    u32*    u2  = (u32*)(KQ + (size_t)NS * HH);       // BB*(LL/2)*HH + 16-row pad

    prep_kernel<<<LN_BLKS + 64 + NN, 256, 0, stream>>>(x, lnw, lnb, Cr, Ci,
                                                       LR, LI, u2, Cpk, PQ);
    build_kt<<<(TT / 2) * 4, 512, 0, stream>>>(Cpk, PQ, KT);
    pack_k<<<NS * HH / 256, 256, 0, stream>>>(KT, KQ);
    conv_kernel<<<BB * (LL / (8 * LT)) * 8, 512, 0, stream>>>(u2, KQ, KT, Dp, y);
}